// Round 2
// baseline (699.850 us; speedup 1.0000x reference)
//
#include <hip/hip_runtime.h>

typedef __attribute__((ext_vector_type(8))) short short8;
typedef __attribute__((ext_vector_type(4))) float f32x4;
typedef __attribute__((ext_vector_type(16))) float f32x16;
typedef __attribute__((ext_vector_type(4))) unsigned short us4;

#define MFMA16(a,b,c) __builtin_amdgcn_mfma_f32_16x16x32_bf16((a),(b),(c),0,0,0)
#define MFMA32(a,b,c) __builtin_amdgcn_mfma_f32_32x32x16_bf16((a),(b),(c),0,0,0)

__device__ __forceinline__ unsigned short f2bf(float f) {
  union { float f; unsigned u; } v; v.f = f;
  return (unsigned short)((v.u + 0x7fffu + ((v.u >> 16) & 1u)) >> 16);
}
__device__ __forceinline__ float bf2f(unsigned short h) {
  union { unsigned u; float f; } v; v.u = ((unsigned)h) << 16;
  return v.f;
}
__device__ __forceinline__ f32x16 zero16() {
  f32x16 v;
  #pragma unroll
  for (int i = 0; i < 16; ++i) v[i] = 0.f;
  return v;
}

// ---------------- prep: weights fp32 -> bf16, N-major (transposed) ----------
__global__ __launch_bounds__(256) void k_prep(
    const float* __restrict__ w1, const float* __restrict__ w2,
    const float* __restrict__ w3, const float* __restrict__ w4,
    const float* __restrict__ w5,
    const float* __restrict__ b1, const float* __restrict__ b2,
    const float* __restrict__ b3, const float* __restrict__ b4,
    const float* __restrict__ b5,
    const float* __restrict__ wa1, const float* __restrict__ wa2,
    const float* __restrict__ wo,
    unsigned short* __restrict__ wtc, unsigned short* __restrict__ w1t,
    unsigned short* __restrict__ w2t, unsigned short* __restrict__ wot,
    float* __restrict__ bcat)
{
  int i = blockIdx.x * 256 + threadIdx.x;
  if (i < 356352) {                       // conv weights [29][64][192]
    int c = i % 192; int rest = i / 192; int n = rest & 63; int tg = rest >> 6;
    const float* w; int j;
    if (tg < 3)       { w = w1; j = tg; }
    else if (tg < 6)  { w = w2; j = tg - 3; }
    else if (tg < 11) { w = w3; j = tg - 6; }
    else if (tg < 20) { w = w4; j = tg - 11; }
    else              { w = w5; j = tg - 20; }
    wtc[i] = f2bf(w[(j * 192 + c) * 64 + n]);
    return;
  }
  i -= 356352;
  if (i < 25600) { int k = i % 320, h = i / 320; w1t[i] = f2bf(wa1[k * 80 + h]); return; }
  i -= 25600;
  if (i < 30720) { int k = i % 96, f = i / 96;
    w2t[i] = (k < 80) ? f2bf(wa2[k * 320 + f]) : (unsigned short)0; return; }
  i -= 30720;
  if (i < 102400) { int f = i % 320, g = i / 320; wot[i] = f2bf(wo[f * 320 + g]); return; }
  i -= 102400;
  if (i < 320) {
    float v;
    if (i < 64)       v = b1[i];
    else if (i < 128) v = b2[i - 64];
    else if (i < 192) v = b3[i - 128];
    else if (i < 256) v = b4[i - 192];
    else              v = b5[i - 256];
    bcat[i] = v;
  }
}

// ---------------- conv: 5 causal dilated branches -> xc bf16 [M][320] -------
// 512 threads, 8 waves, 32x32x16 MFMA. Each 32x32 output tile owned by one
// wave; static schedule balances tap counts (max 180 vs avg 174 MFMA/wave).
__global__ __launch_bounds__(512, 4) void k_conv(
    const float* __restrict__ x, const unsigned short* __restrict__ wtc,
    const float* __restrict__ bcat, unsigned short* __restrict__ xc)
{
  __shared__ unsigned short xs[160 * 196];   // 62720 B, stride 98 dw == 2 mod 32
  int bid = blockIdx.x;
  bid = (bid & 7) * 256 + (bid >> 3);        // XCD swizzle (2048 % 8 == 0)
  const int m0 = bid * 64;
  const int b  = m0 >> 12;
  const int t0 = m0 & 4095;
  const int tid = threadIdx.x;

  const float* xb = x + (size_t)b * 4096 * 192;
  for (int c = tid; c < 160 * 48; c += 512) {
    int r = c / 48, f = c - r * 48;
    int tp = t0 - 96 + r;
    float4 v = make_float4(0.f, 0.f, 0.f, 0.f);
    if (tp >= 0) v = *(const float4*)(xb + (size_t)tp * 192 + f * 4);
    us4 o = { f2bf(v.x), f2bf(v.y), f2bf(v.z), f2bf(v.w) };
    *(us4*)(&xs[r * 196 + f * 4]) = o;
  }
  __syncthreads();

  const int wid = tid >> 6, lane = tid & 63;
  const int l31 = lane & 31, lh = lane >> 5;
  const int lo = wid & 1, mt = (wid >> 1) & 1;
  // wid 0-3: n-tiles {6+lo, 4+lo}; wid 4-7: {8+lo, lo, 2+lo}
  const int ntl = (wid < 4) ? 2 : 3;
  int nts0 = (wid < 4) ? (6 + lo) : (8 + lo);
  int nts1 = (wid < 4) ? (4 + lo) : lo;
  int nts2 = 2 + lo;

  #pragma unroll
  for (int ti = 0; ti < 3; ++ti) {
    if (ti >= ntl) break;
    const int nt = (ti == 0) ? nts0 : (ti == 1) ? nts1 : nts2;
    const int br = nt >> 1, nw = nt & 1;
    const int kt = (0x99533  >> (br * 4)) & 15;         // taps  {3,3,5,9,9}
    const int dl = (0xC8421  >> (br * 4)) & 15;         // dil   {1,2,4,8,12}
    const int tb = (int)((0x140B060300ull >> (br * 8)) & 255); // base {0,3,6,11,20}
    f32x16 accA = zero16(), accB = zero16();
    const int abase = 96 + mt * 32 + l31;
    for (int j = 0; j < kt; ++j) {
      const int roff = abase - dl * (kt - 1 - j);        // causal offset
      const unsigned short* xr = &xs[roff * 196 + lh * 8];
      const unsigned short* wr =
          wtc + ((size_t)((tb + j) * 64 + nw * 32 + l31)) * 192 + lh * 8;
      #pragma unroll
      for (int ks = 0; ks < 12; ks += 2) {
        short8 a0 = *(const short8*)(xr + ks * 16);
        short8 b0 = *(const short8*)(wr + ks * 16);
        accA = MFMA32(a0, b0, accA);
        short8 a1 = *(const short8*)(xr + ks * 16 + 16);
        short8 b1 = *(const short8*)(wr + ks * 16 + 16);
        accB = MFMA32(a1, b1, accB);
      }
    }
    const float bias = bcat[nt * 32 + l31];
    unsigned short* dst = xc + (size_t)(m0 + mt * 32) * 320 + nt * 32 + l31;
    #pragma unroll
    for (int r = 0; r < 16; ++r) {
      int row = (r & 3) + 8 * (r >> 2) + 4 * lh;
      float v = accA[r] + accB[r] + bias;
      v = v > 0.f ? v : 0.f;
      dst[(size_t)row * 320] = f2bf(v);
    }
  }
}

// ---------------- gate: att1->att2; xa = xc*att2 in-place -------------------
// M=128, 512 threads, 8 waves x 16 rows. W-tiles double-buffered (phase 1).
__global__ __launch_bounds__(512, 4) void k_gate(
    unsigned short* __restrict__ xc, const unsigned short* __restrict__ w1t,
    const unsigned short* __restrict__ w2t,
    const float* __restrict__ ba1, const float* __restrict__ ba2)
{
  __shared__ unsigned short a1[128 * 104];   // 26.6 KB
  __shared__ unsigned short bt[11520];       // 23 KB: ph1 dbuf 2x2880, ph2 [320][36]
  const int m0 = blockIdx.x * 128;
  const int tid = threadIdx.x;
  const int wid = tid >> 6, lane = tid & 63, lg = lane >> 4, lr = lane & 15;
  const f32x4 fz = {0.f, 0.f, 0.f, 0.f};

  for (int c = tid; c < 128 * 16; c += 512)      // zero a1 K-pad cols 80..95
    a1[(c >> 4) * 104 + 80 + (c & 15)] = 0;

  // phase 1: att1 = relu(xc @ W1 + b1); A from global, B dbuf in LDS
  if (tid < 320) {
    int n = tid >> 2, ko = (tid & 3) * 8;
    *(short8*)(&bt[n * 36 + ko]) = *(const short8*)(w1t + n * 320 + ko);
  }
  f32x4 acc1[5] = {fz, fz, fz, fz, fz};
  const unsigned short* arow = xc + (size_t)(m0 + wid * 16 + lr) * 320 + lg * 8;
  __syncthreads();
  int buf = 0;
  for (int ks = 0; ks < 10; ++ks) {
    if (ks < 9 && tid < 320) {
      int n = tid >> 2, ko = (tid & 3) * 8;
      *(short8*)(&bt[(buf ^ 1) * 2880 + n * 36 + ko]) =
          *(const short8*)(w1t + n * 320 + (ks + 1) * 32 + ko);
    }
    short8 af = *(const short8*)(arow + ks * 32);
    #pragma unroll
    for (int nf = 0; nf < 5; ++nf) {
      short8 bf = *(const short8*)(&bt[buf * 2880 + (nf * 16 + lr) * 36 + lg * 8]);
      acc1[nf] = MFMA16(af, bf, acc1[nf]);
    }
    __syncthreads();
    buf ^= 1;
  }
  #pragma unroll
  for (int nf = 0; nf < 5; ++nf) {
    float bias = ba1[nf * 16 + lr];
    #pragma unroll
    for (int rg = 0; rg < 4; ++rg) {
      float v = acc1[nf][rg] + bias;
      v = v > 0.f ? v : 0.f;
      a1[(wid * 16 + lg * 4 + rg) * 104 + nf * 16 + lr] = f2bf(v);
    }
  }

  // phase 2: att2 = sigmoid(a1 @ W2 + b2); B single-buffered (3 steps)
  f32x4 acc2[20];
  #pragma unroll
  for (int i = 0; i < 20; ++i) acc2[i] = fz;
  for (int ks = 0; ks < 3; ++ks) {
    __syncthreads();
    for (int c = tid; c < 1280; c += 512) {
      int n = c >> 2, ko = (c & 3) * 8;
      *(short8*)(&bt[n * 36 + ko]) = *(const short8*)(w2t + n * 96 + ks * 32 + ko);
    }
    __syncthreads();
    short8 af = *(const short8*)(&a1[(wid * 16 + lr) * 104 + ks * 32 + lg * 8]);
    #pragma unroll
    for (int nf = 0; nf < 20; ++nf) {
      short8 bf = *(const short8*)(&bt[(nf * 16 + lr) * 36 + lg * 8]);
      acc2[nf] = MFMA16(af, bf, acc2[nf]);
    }
  }
  // phase 3: xa = xc * sigmoid, in-place (same lane reads then writes)
  unsigned short* xrow = xc + (size_t)(m0 + wid * 16) * 320;
  #pragma unroll
  for (int nf = 0; nf < 20; ++nf) {
    float bias = ba2[nf * 16 + lr];
    #pragma unroll
    for (int rg = 0; rg < 4; ++rg) {
      float v = acc2[nf][rg] + bias;
      float s = 1.f / (1.f + __expf(-v));
      size_t idx = (size_t)(lg * 4 + rg) * 320 + nf * 16 + lr;
      xrow[idx] = f2bf(bf2f(xrow[idx]) * s);
    }
  }
}

// ---------------- out: out = xa @ W_out + b_out, 32x32x16, dbuf B ----------
// M=128, 512 threads: wave = (mt = wid>>1) 32 rows x (nh = wid&1) 160 cols.
__global__ __launch_bounds__(512, 4) void k_out(
    const unsigned short* __restrict__ xa, const unsigned short* __restrict__ wot,
    const float* __restrict__ bo, float* __restrict__ out)
{
  __shared__ unsigned short bt[12800];       // 2 x [320][20] = 25.6 KB
  const int m0 = blockIdx.x * 128;
  const int tid = threadIdx.x;
  const int wid = tid >> 6, lane = tid & 63;
  const int l31 = lane & 31, lh = lane >> 5;
  const int mt = wid >> 1, nh = wid & 1;

  f32x16 acc[5];
  #pragma unroll
  for (int i = 0; i < 5; ++i) acc[i] = zero16();

  // prologue stage ks=0
  for (int c = tid; c < 640; c += 512) {
    int n = c >> 1, ko = (c & 1) * 8;
    *(short8*)(&bt[n * 20 + ko]) = *(const short8*)(wot + n * 320 + ko);
  }
  const unsigned short* ar = xa + (size_t)(m0 + mt * 32 + l31) * 320 + lh * 8;
  __syncthreads();
  int buf = 0;
  for (int ks = 0; ks < 20; ++ks) {
    if (ks < 19) {
      for (int c = tid; c < 640; c += 512) {
        int n = c >> 1, ko = (c & 1) * 8;
        *(short8*)(&bt[(buf ^ 1) * 6400 + n * 20 + ko]) =
            *(const short8*)(wot + n * 320 + (ks + 1) * 16 + ko);
      }
    }
    short8 af = *(const short8*)(ar + ks * 16);
    #pragma unroll
    for (int j = 0; j < 5; ++j) {
      short8 bf = *(const short8*)(&bt[buf * 6400 + (nh * 160 + j * 32 + l31) * 20 + lh * 8]);
      acc[j] = MFMA32(af, bf, acc[j]);
    }
    __syncthreads();
    buf ^= 1;
  }
  float* orow = out + (size_t)(m0 + mt * 32) * 320 + nh * 160;
  #pragma unroll
  for (int j = 0; j < 5; ++j) {
    float bias = bo[nh * 160 + j * 32 + l31];
    #pragma unroll
    for (int r = 0; r < 16; ++r) {
      int row = (r & 3) + 8 * (r >> 2) + 4 * lh;
      orow[(size_t)row * 320 + j * 32 + l31] = acc[j][r] + bias;
    }
  }
}

// ---------------- host ------------------------------------------------------
extern "C" void kernel_launch(void* const* d_in, const int* in_sizes, int n_in,
                              void* d_out, int out_size, void* d_ws, size_t ws_size,
                              hipStream_t stream) {
  const float* x    = (const float*)d_in[0];
  const float* w_b1 = (const float*)d_in[1];  const float* b_b1 = (const float*)d_in[2];
  const float* w_b2 = (const float*)d_in[3];  const float* b_b2 = (const float*)d_in[4];
  const float* w_b3 = (const float*)d_in[5];  const float* b_b3 = (const float*)d_in[6];
  const float* w_b4 = (const float*)d_in[7];  const float* b_b4 = (const float*)d_in[8];
  const float* w_b5 = (const float*)d_in[9];  const float* b_b5 = (const float*)d_in[10];
  const float* wa1  = (const float*)d_in[11]; const float* ba1  = (const float*)d_in[12];
  const float* wa2  = (const float*)d_in[13]; const float* ba2  = (const float*)d_in[14];
  const float* wo   = (const float*)d_in[15]; const float* bo   = (const float*)d_in[16];

  char* ws = (char*)d_ws;
  unsigned short* xc  = (unsigned short*)(ws);              // 83,886,080 B
  unsigned short* wtc = (unsigned short*)(ws + 83886080);   // 712,704
  unsigned short* w1t = (unsigned short*)(ws + 84598784);   // 51,200
  unsigned short* w2t = (unsigned short*)(ws + 84649984);   // 61,440
  unsigned short* wot = (unsigned short*)(ws + 84711424);   // 204,800
  float*          bct = (float*)         (ws + 84916224);   // 1,280

  k_prep<<<2014, 256, 0, stream>>>(w_b1, w_b2, w_b3, w_b4, w_b5,
                                   b_b1, b_b2, b_b3, b_b4, b_b5,
                                   wa1, wa2, wo, wtc, w1t, w2t, wot, bct);
  k_conv<<<2048, 512, 0, stream>>>(x, wtc, bct, xc);
  k_gate<<<1024, 512, 0, stream>>>(xc, w1t, w2t, ba1, ba2);
  k_out <<<1024, 512, 0, stream>>>(xc, wot, bo, (float*)d_out);
}